// Round 3
// baseline (1006.463 us; speedup 1.0000x reference)
//
#include <hip/hip_runtime.h>
#include <hip/hip_bf16.h>

// GlobalLocalAttention on MI355X — fused pool+depthwise revision.
// Regions: A=[0,64MiB) x_t -> dwt ; B=[64,160MiB) qkv_half -> dw_nchw(bf16) ;
//          C=[160,224MiB) local(bf16) ; W=weights (~1.7MB).
// d_out doubles as the f32 attention-output scratch (final GEMM rewrites it).

typedef __bf16 bf16x8 __attribute__((ext_vector_type(8)));
typedef float  f32x4  __attribute__((ext_vector_type(4)));
typedef unsigned short u16;

#define HWPIX 65536
#define NPIX  131072

__device__ __forceinline__ u16 f2bf(float f) {
    union { float f; unsigned u; } v; v.f = f;
    return (u16)((v.u + 0x7fffu + ((v.u >> 16) & 1u)) >> 16);
}
__device__ __forceinline__ float bf2f(u16 h) {
    union { unsigned u; float f; } v; v.u = ((unsigned)h) << 16;
    return v.f;
}

#define GLDS16(gp, lp) __builtin_amdgcn_global_load_lds( \
    (__attribute__((address_space(1))) void*)(gp), \
    (__attribute__((address_space(3))) void*)(lp), 16, 0, 0)

// ---------------------------------------------------------------------------
__global__ void prep_weights(const float* __restrict__ w_qkv,
                             const float* __restrict__ w_l1,
                             const float* __restrict__ bn1g, const float* __restrict__ bn1b,
                             const float* __restrict__ w_l2,
                             const float* __restrict__ bn2g, const float* __restrict__ bn2b,
                             const float* __restrict__ w_pw,
                             const float* __restrict__ bn3g, const float* __restrict__ bn3b,
                             u16* __restrict__ wl, u16* __restrict__ wq, u16* __restrict__ wpw,
                             float* __restrict__ bias_l, float* __restrict__ bias_pw,
                             u16* __restrict__ zeros)
{
    const int tid = threadIdx.x;
    if (blockIdx.x >= 256) {
        int row = blockIdx.x - 256;              // 0..767
        wq[row * 256 + tid] = f2bf(w_qkv[row * 256 + tid]);
        return;
    }
    const int oc = blockIdx.x, ic = tid;
    const float rs = rsqrtf(1.f + 1e-5f);
    const float s1 = bn1g[oc] * rs;
    const float s2 = bn2g[oc] * rs;
    const float w2v = w_l2[oc * 256 + ic] * s2;
    #pragma unroll
    for (int tap = 0; tap < 9; ++tap) {
        float v = s1 * w_l1[(oc * 256 + ic) * 9 + tap];
        if (tap == 4) v += w2v;
        wl[oc * 2304 + tap * 256 + ic] = f2bf(v);
    }
    const float s3 = bn3g[ic] * rs;
    const float wp = w_pw[oc * 256 + ic];
    wpw[oc * 256 + ic] = f2bf(wp * s3);

    __shared__ float red[256];
    red[ic] = wp * bn3b[ic];
    __syncthreads();
    for (int s = 128; s > 0; s >>= 1) {
        if (ic < s) red[ic] += red[ic + s];
        __syncthreads();
    }
    if (ic == 0) {
        bias_pw[oc] = red[0];
        bias_l[oc]  = bn1b[oc] + bn2b[oc];
    }
    if (blockIdx.x == 0) zeros[tid] = 0;
}

// ---------------------------------------------------------------------------
template <typename TIN>
__device__ __forceinline__ float ldval(const TIN* p);
template <> __device__ __forceinline__ float ldval<float>(const float* p) { return *p; }
template <> __device__ __forceinline__ float ldval<u16>(const u16* p)     { return bf2f(*p); }

template <typename TIN>
__global__ __launch_bounds__(256)
void to_chlast(const TIN* __restrict__ in, u16* __restrict__ out)
{
    __shared__ float L[32][65];
    const int tid = threadIdx.x;
    const int p0 = blockIdx.x * 64;
    const int b = p0 >> 16, pin = p0 & 65535;
    const TIN* src = in + (size_t)b * 256 * HWPIX + pin;
    for (int cb = 0; cb < 256; cb += 32) {
        #pragma unroll
        for (int e = 0; e < 8; ++e) {
            int idx = e * 256 + tid;
            int row = idx >> 6, px = idx & 63;
            L[row][px] = ldval(src + (size_t)(cb + row) * HWPIX + px);
        }
        __syncthreads();
        const int px = tid >> 2, cq = tid & 3;
        u16 t[8];
        #pragma unroll
        for (int e = 0; e < 8; ++e) t[e] = f2bf(L[cq * 8 + e][px]);
        uint4 v;
        v.x = (unsigned)t[0] | ((unsigned)t[1] << 16);
        v.y = (unsigned)t[2] | ((unsigned)t[3] << 16);
        v.z = (unsigned)t[4] | ((unsigned)t[5] << 16);
        v.w = (unsigned)t[6] | ((unsigned)t[7] << 16);
        *(uint4*)(out + (size_t)(p0 + px) * 256 + cb + cq * 8) = v;
        __syncthreads();
    }
}

// ---------------------------------------------------------------------------
// Implicit-GEMM conv (1x1 or 3x3): 128px x 128oc tile, BK=32, GLDS(16B),
// mfma_f32_16x16x32_bf16. Output plane index = bb*out_c + (oc - oc_off).
template <int NTAPS, bool OUT_BF16, bool HAS_BIAS>
__global__ __launch_bounds__(256)
void gemm_conv(const u16* __restrict__ X,
               const u16* __restrict__ Wm,
               const float* __restrict__ bias,
               void* __restrict__ outv,
               const u16* __restrict__ zeros,
               int oc_off, int out_c)
{
    constexpr int K = NTAPS * 256;
    __shared__ __align__(16) u16 Wt[128 * 32];
    __shared__ __align__(16) u16 Xt[128 * 32];

    const int tid   = threadIdx.x;
    const int wv    = tid >> 6;
    const int lane  = tid & 63;
    const int pbase = blockIdx.x * 128;
    const int obase = blockIdx.y * 128 + oc_off;
    const int srow  = wv * 16 + (lane >> 2);
    const int sslot = lane & 3;
    const int wr = wv >> 1, wc = wv & 1;

    f32x4 acc[4][4];
    #pragma unroll
    for (int o = 0; o < 4; ++o)
        #pragma unroll
        for (int p = 0; p < 4; ++p)
            acc[o][p] = (f32x4){0.f, 0.f, 0.f, 0.f};

    for (int tap = 0; tap < NTAPS; ++tap) {
        const u16* xsrc[2];
        const u16* wsrc[2];
        #pragma unroll
        for (int i = 0; i < 2; ++i) {
            const int row = i * 64 + srow;
            const int p = pbase + row;
            const u16* sp;
            if (NTAPS == 9) {
                const int dy = tap / 3 - 1, dx = tap % 3 - 1;
                const int h = (p >> 8) & 255, w = p & 255;
                const int hh = h + dy, ww = w + dx;
                if ((unsigned)hh < 256u && (unsigned)ww < 256u)
                    sp = X + (size_t)(p + dy * 256 + dx) * 256 + sslot * 8;
                else
                    sp = zeros + sslot * 8;
            } else {
                sp = X + (size_t)p * 256 + sslot * 8;
            }
            xsrc[i] = sp;
            wsrc[i] = Wm + (size_t)(obase + row) * K + tap * 256 + sslot * 8;
        }

        for (int kc = 0; kc < 256; kc += 32) {
            GLDS16(wsrc[0] + kc, &Wt[(wv * 16) * 32]);
            GLDS16(wsrc[1] + kc, &Wt[(64 + wv * 16) * 32]);
            GLDS16(xsrc[0] + kc, &Xt[(wv * 16) * 32]);
            GLDS16(xsrc[1] + kc, &Xt[(64 + wv * 16) * 32]);
            __syncthreads();

            bf16x8 afr[4], bfr[4];
            #pragma unroll
            for (int o = 0; o < 4; ++o)
                afr[o] = *(const bf16x8*)&Wt[(wr * 64 + o * 16 + (lane & 15)) * 32 + (lane >> 4) * 8];
            #pragma unroll
            for (int p = 0; p < 4; ++p)
                bfr[p] = *(const bf16x8*)&Xt[(wc * 64 + p * 16 + (lane & 15)) * 32 + (lane >> 4) * 8];
            #pragma unroll
            for (int o = 0; o < 4; ++o)
                #pragma unroll
                for (int p = 0; p < 4; ++p)
                    acc[o][p] = __builtin_amdgcn_mfma_f32_16x16x32_bf16(afr[o], bfr[p], acc[o][p], 0, 0, 0);
            __syncthreads();
        }
    }

    const int r0 = (lane >> 4) * 4;
    const int cl = lane & 15;
    #pragma unroll
    for (int o = 0; o < 4; ++o) {
        const int oc = obase + wr * 64 + o * 16 + r0;
        #pragma unroll
        for (int p = 0; p < 4; ++p) {
            const int px = pbase + wc * 64 + p * 16 + cl;
            const int bb = px >> 16, pin = px & 65535;
            const size_t base = ((size_t)bb * out_c + (oc - oc_off)) * HWPIX + pin;
            #pragma unroll
            for (int r = 0; r < 4; ++r) {
                float v = acc[o][p][r];
                if (HAS_BIAS) v += bias[oc + r];
                if (OUT_BF16) ((u16*)outv)[base + (size_t)r * HWPIX] = f2bf(v);
                else          ((float*)outv)[base + (size_t)r * HWPIX] = v;
            }
        }
    }
}

// ---------------------------------------------------------------------------
__device__ __forceinline__ void unp8(uint4 u, float* f) {
    f[0] = bf2f((u16)(u.x & 0xffff)); f[1] = bf2f((u16)(u.x >> 16));
    f[2] = bf2f((u16)(u.y & 0xffff)); f[3] = bf2f((u16)(u.y >> 16));
    f[4] = bf2f((u16)(u.z & 0xffff)); f[5] = bf2f((u16)(u.z >> 16));
    f[6] = bf2f((u16)(u.w & 0xffff)); f[7] = bf2f((u16)(u.w >> 16));
}

// One wave per (window, head); lane = query token. qkvh = half-buffer
// [2][384][65536] bf16 (NCHW planes c' = c - 384*half). i1 = i1l + i1_off.
__global__ __launch_bounds__(64)
void attn_win(const u16* __restrict__ qkvh,
              const float* __restrict__ rpb,
              float* __restrict__ outb, int i1_off)
{
    __shared__ float kls[64][16];
    __shared__ float vls[64][16];
    const int bid = blockIdx.x;               // 16384 blocks
    const int head = bid & 15;
    const int m = bid >> 4;                   // 0..1023
    const int b = m >> 9, i1l = (m >> 5) & 15, i3 = m & 31;
    const int t = threadIdx.x;
    const int i2 = t >> 3, i4 = t & 7;
    const size_t toff = (size_t)b * 25165824 + (size_t)i1l * 1572864 +
                        (size_t)i2 * 196608 + (size_t)i3 * 6144 + (size_t)i4 * 768 +
                        (size_t)head * 16;
    const uint4* qp = (const uint4*)(qkvh + toff);
    const uint4 q0 = qp[0],  q1 = qp[1];
    const uint4 k0 = qp[32], k1 = qp[33];
    const uint4 v0 = qp[64], v1 = qp[65];
    float qf[16], tmp[16];
    unp8(q0, qf); unp8(q1, qf + 8);
    unp8(k0, tmp); unp8(k1, tmp + 8);
    #pragma unroll
    for (int d = 0; d < 16; ++d) kls[t][d] = tmp[d];
    unp8(v0, tmp); unp8(v1, tmp + 8);
    #pragma unroll
    for (int d = 0; d < 16; ++d) vls[t][d] = tmp[d];
    __syncthreads();

    const int qi = t >> 3, qj = t & 7;
    float s[64];
    float mx = -1e30f;
    #pragma unroll
    for (int kt = 0; kt < 64; ++kt) {
        const float4 a  = *(const float4*)&kls[kt][0];
        const float4 b4 = *(const float4*)&kls[kt][4];
        const float4 c4 = *(const float4*)&kls[kt][8];
        const float4 d4 = *(const float4*)&kls[kt][12];
        float dot = qf[0]*a.x  + qf[1]*a.y  + qf[2]*a.z  + qf[3]*a.w
                  + qf[4]*b4.x + qf[5]*b4.y + qf[6]*b4.z + qf[7]*b4.w
                  + qf[8]*c4.x + qf[9]*c4.y + qf[10]*c4.z + qf[11]*c4.w
                  + qf[12]*d4.x+ qf[13]*d4.y+ qf[14]*d4.z+ qf[15]*d4.w;
        const int ki = kt >> 3, kj = kt & 7;
        const float val = dot * 0.25f + rpb[((qi - ki + 7) * 15 + (qj - kj + 7)) * 16 + head];
        s[kt] = val;
        mx = fmaxf(mx, val);
    }
    float l = 0.f;
    #pragma unroll
    for (int kt = 0; kt < 64; ++kt) { float e = __expf(s[kt] - mx); s[kt] = e; l += e; }
    const float inv = 1.f / l;
    float o[16];
    #pragma unroll
    for (int d = 0; d < 16; ++d) o[d] = 0.f;
    #pragma unroll
    for (int kt = 0; kt < 64; ++kt) {
        const float w = s[kt];
        const float4 a  = *(const float4*)&vls[kt][0];
        const float4 b4 = *(const float4*)&vls[kt][4];
        const float4 c4 = *(const float4*)&vls[kt][8];
        const float4 d4 = *(const float4*)&vls[kt][12];
        o[0] += w*a.x;  o[1] += w*a.y;  o[2]  += w*a.z;  o[3]  += w*a.w;
        o[4] += w*b4.x; o[5] += w*b4.y; o[6]  += w*b4.z; o[7]  += w*b4.w;
        o[8] += w*c4.x; o[9] += w*c4.y; o[10] += w*c4.z; o[11] += w*c4.w;
        o[12]+= w*d4.x; o[13]+= w*d4.y; o[14] += w*d4.z; o[15] += w*d4.w;
    }
    const int n = b * 1024 + (i1l + i1_off) * 32 + i3;   // global window id
    float* op = outb + ((size_t)(n * 16 + head) << 10) + t * 16;
    #pragma unroll
    for (int d = 0; d < 16; ++d) op[d] = o[d] * inv;
}

// ---------------------------------------------------------------------------
// Fused pool(ax+ay)+local-add+reflect-pad+depthwise-8x8, one 32x64 output
// tile per block. outsum = 0.125*(V8+H8)+local computed in LDS via sliding
// box sums; dw consumed via register-blocked 2x4 outputs with ds_read_b128.
// Extension rule everywhere: idx==256 -> 254, outside [0,256] -> 0.
__global__ __launch_bounds__(256)
void pool_dw_fused(const float* __restrict__ attn,   // f32 [512][65536] (d_out scratch)
                   const u16* __restrict__ local,    // bf16 [512][65536]
                   const float* __restrict__ wdw,    // f32 [256][64]
                   u16* __restrict__ dwo)            // bf16 [512][65536]
{
    __shared__ float Sa[46][80];   // A_ext tile: rows TH-6..TH+39, cols TW-6..TW+71
    __shared__ float Sv[39][76];   // V8 at pooled coords
    __shared__ float Sp[39][76];   // outsum_ext at pooled coords
    __shared__ float wk[64];

    const int bid   = blockIdx.x;
    const int plane = bid >> 5;            // 512 planes
    const int c     = plane & 255;
    const int tile  = bid & 31;            // 8 row-tiles x 4 col-tiles
    const int TH    = (tile >> 2) * 32;
    const int TW    = (tile & 3) * 64;
    const int tid   = threadIdx.x;
    const float* A  = attn + (size_t)plane * HWPIX;
    const u16*   L  = local + (size_t)plane * HWPIX;

    if (tid < 64) wk[tid] = wdw[c * 64 + tid];

    // Phase A: load A_ext tile (46x78) into Sa
    for (int idx = tid; idx < 46 * 78; idx += 256) {
        const int i = idx / 78, j = idx - i * 78;
        const int gh = TH + i - 6, gw = TW + j - 6;
        const int eh = (gh == 256) ? 254 : gh;
        const int ew = (gw == 256) ? 254 : gw;
        float v = 0.f;
        if ((unsigned)eh < 256u && (unsigned)ew < 256u) v = A[eh * 256 + ew];
        Sa[i][j] = v;
    }
    __syncthreads();

    // Phase B: vertical 8-box sums. unit = col c0 (71) x seg (3 of 13 rows)
    if (tid < 213) {
        const int cc  = tid / 3;
        const int seg = tid - cc * 3;
        const int r0  = seg * 13;
        float s = 0.f;
        #pragma unroll
        for (int t = 0; t < 8; ++t) s += Sa[r0 + t][cc + 3];
        #pragma unroll
        for (int i = 0; i < 13; ++i) {
            const int r = r0 + i;
            Sv[r][cc] = s;
            if (i < 12) s += Sa[r + 8][cc + 3] - Sa[r][cc + 3];
        }
    }
    __syncthreads();

    // Phase C: Sp[r][c] = outsum_ext value. unit = row r (39) x seg (6 of 12 cols)
    if (tid < 234) {
        const int r   = tid / 6;
        const int seg = tid - r * 6;
        const int c0  = seg * 12;
        const int cend = (c0 + 12 < 71) ? c0 + 12 : 71;
        const int gr = TH + r - 3;
        const bool rv = (gr >= 0) && (gr <= 256);
        const int er = (gr == 256) ? 254 : gr;
        const int rs = er - TH + 3;         // source pooled-row (always in [0,39))
        float h8 = 0.f;
        #pragma unroll
        for (int t = 0; t < 8; ++t) h8 += Sa[rs + 3][c0 + t];
        for (int cc = c0; cc < cend; ++cc) {
            float val = 0.f;
            if (rv) {
                const int gc = TW + cc - 3;
                if ((unsigned)gc < 256u) {
                    val = 0.125f * (Sv[rs][cc] + h8) + bf2f(L[er * 256 + gc]);
                } else if (gc == 256) {       // only TW==192, cc==67 -> source col 65
                    float h = 0.f;
                    #pragma unroll
                    for (int t = 0; t < 8; ++t) h += Sa[rs + 3][65 + t];
                    val = 0.125f * (Sv[rs][65] + h) + bf2f(L[er * 256 + 254]);
                }
            }
            Sp[r][cc] = val;
            if (cc + 1 < cend) h8 += Sa[rs + 3][cc + 8] - Sa[rs + 3][cc];
        }
    }
    __syncthreads();

    // Phase D: depthwise 8x8, thread = 2 rows x 4 cols of outputs
    float wreg[64];
    #pragma unroll
    for (int i = 0; i < 64; ++i) wreg[i] = wk[i];

    const int rb = tid >> 4;               // 16 row-blocks of 2
    const int cb = tid & 15;               // 16 col-blocks of 4
    const int oy2 = rb * 2, ox4 = cb * 4;
    float acc[2][4];
    #pragma unroll
    for (int q = 0; q < 2; ++q)
        #pragma unroll
        for (int j = 0; j < 4; ++j) acc[q][j] = 0.f;

    #pragma unroll
    for (int r = 0; r < 9; ++r) {
        const float4 ra = *(const float4*)&Sp[oy2 + r][ox4];
        const float4 rb4 = *(const float4*)&Sp[oy2 + r][ox4 + 4];
        const float4 rc = *(const float4*)&Sp[oy2 + r][ox4 + 8];
        const float row[12] = {ra.x, ra.y, ra.z, ra.w, rb4.x, rb4.y, rb4.z, rb4.w,
                               rc.x, rc.y, rc.z, rc.w};
        #pragma unroll
        for (int q = 0; q < 2; ++q) {
            const int kh = r - q;
            if (kh >= 0 && kh < 8) {
                #pragma unroll
                for (int kw = 0; kw < 8; ++kw) {
                    const float w = wreg[kh * 8 + kw];
                    #pragma unroll
                    for (int j = 0; j < 4; ++j)
                        acc[q][j] += w * row[j + kw];
                }
            }
        }
    }
    u16* O = dwo + (size_t)plane * HWPIX;
    #pragma unroll
    for (int q = 0; q < 2; ++q) {
        ushort4 pk;
        pk.x = f2bf(acc[q][0]); pk.y = f2bf(acc[q][1]);
        pk.z = f2bf(acc[q][2]); pk.w = f2bf(acc[q][3]);
        *(ushort4*)&O[(TH + oy2 + q) * 256 + TW + ox4] = pk;
    }
}

// ---------------------------------------------------------------------------
extern "C" void kernel_launch(void* const* d_in, const int* in_sizes, int n_in,
                              void* d_out, int out_size, void* d_ws, size_t ws_size,
                              hipStream_t stream)
{
    const float* x     = (const float*)d_in[0];
    const float* w_qkv = (const float*)d_in[1];
    const float* w_l1  = (const float*)d_in[2];
    const float* bn1g  = (const float*)d_in[3];
    const float* bn1b  = (const float*)d_in[4];
    const float* w_l2  = (const float*)d_in[5];
    const float* bn2g  = (const float*)d_in[6];
    const float* bn2b  = (const float*)d_in[7];
    const float* w_dw  = (const float*)d_in[8];
    const float* bn3g  = (const float*)d_in[9];
    const float* bn3b  = (const float*)d_in[10];
    const float* w_pw  = (const float*)d_in[11];
    const float* rpb   = (const float*)d_in[12];
    float* out = (float*)d_out;
    char* ws = (char*)d_ws;

    if (ws_size < (size_t)236587520) return;

    // region A [0, 64MiB): x_t, later dwt
    u16* x_t = (u16*)(ws + 0);
    u16* dwt = (u16*)(ws + 0);
    // region B [64MiB, 160MiB): qkv half (2x384x65536 bf16), later dw_nchw bf16
    u16* qkvh    = (u16*)(ws + 67108864);
    u16* dw_nchw = (u16*)(ws + 67108864);
    // region C [160MiB, 224MiB): local bf16
    u16* localb  = (u16*)(ws + 167772160);
    // weights
    u16*   wl      = (u16*)(ws + 234881024);   // 1,179,648 B
    u16*   wq      = (u16*)(ws + 236060672);   //   393,216 B
    u16*   wpw     = (u16*)(ws + 236453888);   //   131,072 B
    float* bias_l  = (float*)(ws + 236584960);
    float* bias_pw = (float*)(ws + 236585984);
    u16*   zeros   = (u16*)(ws + 236587008);
    float* attnf = out;                        // d_out as f32 attn scratch

    prep_weights<<<1024, 256, 0, stream>>>(w_qkv, w_l1, bn1g, bn1b, w_l2, bn2g, bn2b,
                                           w_pw, bn3g, bn3b, wl, wq, wpw, bias_l, bias_pw, zeros);
    to_chlast<float><<<NPIX / 64, 256, 0, stream>>>(x, x_t);
    gemm_conv<9, true, true><<<dim3(NPIX / 128, 2), 256, 0, stream>>>(
        x_t, wl, bias_l, localb, zeros, 0, 256);
    gemm_conv<1, true, false><<<dim3(NPIX / 128, 3), 256, 0, stream>>>(
        x_t, wq, nullptr, qkvh, zeros, 0, 384);
    attn_win<<<16384, 64, 0, stream>>>(qkvh, rpb, attnf, 0);
    gemm_conv<1, true, false><<<dim3(NPIX / 128, 3), 256, 0, stream>>>(
        x_t, wq, nullptr, qkvh, zeros, 384, 384);
    attn_win<<<16384, 64, 0, stream>>>(qkvh, rpb, attnf, 16);
    // fused pools + local add + depthwise -> bf16 NCHW into region B
    pool_dw_fused<<<16384, 256, 0, stream>>>(attnf, localb, w_dw, dw_nchw);
    to_chlast<u16><<<NPIX / 64, 256, 0, stream>>>(dw_nchw, dwt);
    gemm_conv<1, false, true><<<dim3(NPIX / 128, 2), 256, 0, stream>>>(
        dwt, wpw, bias_pw, out, zeros, 0, 256);
}

// Round 4
// 841.552 us; speedup vs baseline: 1.1960x; 1.1960x over previous
//
#include <hip/hip_runtime.h>
#include <hip/hip_bf16.h>

// GlobalLocalAttention on MI355X — split pool/dw, bank-conflict-free revision.
// Regions: A=[0,64MiB) x_t -> dwt ; B=[64,160MiB) qkvh -> outsum(bf16, first 64MiB) ;
//          C=[160,224MiB) local(bf16) -> dw_nchw(bf16) ; W=weights (~1.7MB).
// d_out doubles as the f32 attention-output scratch (final GEMM rewrites it).

typedef __bf16 bf16x8 __attribute__((ext_vector_type(8)));
typedef float  f32x4  __attribute__((ext_vector_type(4)));
typedef unsigned short u16;

#define HWPIX 65536
#define NPIX  131072

__device__ __forceinline__ u16 f2bf(float f) {
    union { float f; unsigned u; } v; v.f = f;
    return (u16)((v.u + 0x7fffu + ((v.u >> 16) & 1u)) >> 16);
}
__device__ __forceinline__ float bf2f(u16 h) {
    union { unsigned u; float f; } v; v.u = ((unsigned)h) << 16;
    return v.f;
}

#define GLDS16(gp, lp) __builtin_amdgcn_global_load_lds( \
    (__attribute__((address_space(1))) void*)(gp), \
    (__attribute__((address_space(3))) void*)(lp), 16, 0, 0)

// ---------------------------------------------------------------------------
__global__ void prep_weights(const float* __restrict__ w_qkv,
                             const float* __restrict__ w_l1,
                             const float* __restrict__ bn1g, const float* __restrict__ bn1b,
                             const float* __restrict__ w_l2,
                             const float* __restrict__ bn2g, const float* __restrict__ bn2b,
                             const float* __restrict__ w_pw,
                             const float* __restrict__ bn3g, const float* __restrict__ bn3b,
                             u16* __restrict__ wl, u16* __restrict__ wq, u16* __restrict__ wpw,
                             float* __restrict__ bias_l, float* __restrict__ bias_pw,
                             u16* __restrict__ zeros)
{
    const int tid = threadIdx.x;
    if (blockIdx.x >= 256) {
        int row = blockIdx.x - 256;              // 0..767
        wq[row * 256 + tid] = f2bf(w_qkv[row * 256 + tid]);
        return;
    }
    const int oc = blockIdx.x, ic = tid;
    const float rs = rsqrtf(1.f + 1e-5f);
    const float s1 = bn1g[oc] * rs;
    const float s2 = bn2g[oc] * rs;
    const float w2v = w_l2[oc * 256 + ic] * s2;
    #pragma unroll
    for (int tap = 0; tap < 9; ++tap) {
        float v = s1 * w_l1[(oc * 256 + ic) * 9 + tap];
        if (tap == 4) v += w2v;
        wl[oc * 2304 + tap * 256 + ic] = f2bf(v);
    }
    const float s3 = bn3g[ic] * rs;
    const float wp = w_pw[oc * 256 + ic];
    wpw[oc * 256 + ic] = f2bf(wp * s3);

    __shared__ float red[256];
    red[ic] = wp * bn3b[ic];
    __syncthreads();
    for (int s = 128; s > 0; s >>= 1) {
        if (ic < s) red[ic] += red[ic + s];
        __syncthreads();
    }
    if (ic == 0) {
        bias_pw[oc] = red[0];
        bias_l[oc]  = bn1b[oc] + bn2b[oc];
    }
    if (blockIdx.x == 0) zeros[tid] = 0;
}

// ---------------------------------------------------------------------------
template <typename TIN>
__device__ __forceinline__ float ldval(const TIN* p);
template <> __device__ __forceinline__ float ldval<float>(const float* p) { return *p; }
template <> __device__ __forceinline__ float ldval<u16>(const u16* p)     { return bf2f(*p); }

template <typename TIN>
__global__ __launch_bounds__(256)
void to_chlast(const TIN* __restrict__ in, u16* __restrict__ out)
{
    __shared__ float L[32][65];
    const int tid = threadIdx.x;
    const int p0 = blockIdx.x * 64;
    const int b = p0 >> 16, pin = p0 & 65535;
    const TIN* src = in + (size_t)b * 256 * HWPIX + pin;
    for (int cb = 0; cb < 256; cb += 32) {
        #pragma unroll
        for (int e = 0; e < 8; ++e) {
            int idx = e * 256 + tid;
            int row = idx >> 6, px = idx & 63;
            L[row][px] = ldval(src + (size_t)(cb + row) * HWPIX + px);
        }
        __syncthreads();
        const int px = tid >> 2, cq = tid & 3;
        u16 t[8];
        #pragma unroll
        for (int e = 0; e < 8; ++e) t[e] = f2bf(L[cq * 8 + e][px]);
        uint4 v;
        v.x = (unsigned)t[0] | ((unsigned)t[1] << 16);
        v.y = (unsigned)t[2] | ((unsigned)t[3] << 16);
        v.z = (unsigned)t[4] | ((unsigned)t[5] << 16);
        v.w = (unsigned)t[6] | ((unsigned)t[7] << 16);
        *(uint4*)(out + (size_t)(p0 + px) * 256 + cb + cq * 8) = v;
        __syncthreads();
    }
}

// ---------------------------------------------------------------------------
// Implicit-GEMM conv (1x1 or 3x3): 128px x 128oc tile, BK=32, GLDS(16B),
// mfma_f32_16x16x32_bf16. Output plane index = bb*out_c + (oc - oc_off).
template <int NTAPS, bool OUT_BF16, bool HAS_BIAS>
__global__ __launch_bounds__(256)
void gemm_conv(const u16* __restrict__ X,
               const u16* __restrict__ Wm,
               const float* __restrict__ bias,
               void* __restrict__ outv,
               const u16* __restrict__ zeros,
               int oc_off, int out_c)
{
    constexpr int K = NTAPS * 256;
    __shared__ __align__(16) u16 Wt[128 * 32];
    __shared__ __align__(16) u16 Xt[128 * 32];

    const int tid   = threadIdx.x;
    const int wv    = tid >> 6;
    const int lane  = tid & 63;
    const int pbase = blockIdx.x * 128;
    const int obase = blockIdx.y * 128 + oc_off;
    const int srow  = wv * 16 + (lane >> 2);
    const int sslot = lane & 3;
    const int wr = wv >> 1, wc = wv & 1;

    f32x4 acc[4][4];
    #pragma unroll
    for (int o = 0; o < 4; ++o)
        #pragma unroll
        for (int p = 0; p < 4; ++p)
            acc[o][p] = (f32x4){0.f, 0.f, 0.f, 0.f};

    for (int tap = 0; tap < NTAPS; ++tap) {
        const u16* xsrc[2];
        const u16* wsrc[2];
        #pragma unroll
        for (int i = 0; i < 2; ++i) {
            const int row = i * 64 + srow;
            const int p = pbase + row;
            const u16* sp;
            if (NTAPS == 9) {
                const int dy = tap / 3 - 1, dx = tap % 3 - 1;
                const int h = (p >> 8) & 255, w = p & 255;
                const int hh = h + dy, ww = w + dx;
                if ((unsigned)hh < 256u && (unsigned)ww < 256u)
                    sp = X + (size_t)(p + dy * 256 + dx) * 256 + sslot * 8;
                else
                    sp = zeros + sslot * 8;
            } else {
                sp = X + (size_t)p * 256 + sslot * 8;
            }
            xsrc[i] = sp;
            wsrc[i] = Wm + (size_t)(obase + row) * K + tap * 256 + sslot * 8;
        }

        for (int kc = 0; kc < 256; kc += 32) {
            GLDS16(wsrc[0] + kc, &Wt[(wv * 16) * 32]);
            GLDS16(wsrc[1] + kc, &Wt[(64 + wv * 16) * 32]);
            GLDS16(xsrc[0] + kc, &Xt[(wv * 16) * 32]);
            GLDS16(xsrc[1] + kc, &Xt[(64 + wv * 16) * 32]);
            __syncthreads();

            bf16x8 afr[4], bfr[4];
            #pragma unroll
            for (int o = 0; o < 4; ++o)
                afr[o] = *(const bf16x8*)&Wt[(wr * 64 + o * 16 + (lane & 15)) * 32 + (lane >> 4) * 8];
            #pragma unroll
            for (int p = 0; p < 4; ++p)
                bfr[p] = *(const bf16x8*)&Xt[(wc * 64 + p * 16 + (lane & 15)) * 32 + (lane >> 4) * 8];
            #pragma unroll
            for (int o = 0; o < 4; ++o)
                #pragma unroll
                for (int p = 0; p < 4; ++p)
                    acc[o][p] = __builtin_amdgcn_mfma_f32_16x16x32_bf16(afr[o], bfr[p], acc[o][p], 0, 0, 0);
            __syncthreads();
        }
    }

    const int r0 = (lane >> 4) * 4;
    const int cl = lane & 15;
    #pragma unroll
    for (int o = 0; o < 4; ++o) {
        const int oc = obase + wr * 64 + o * 16 + r0;
        #pragma unroll
        for (int p = 0; p < 4; ++p) {
            const int px = pbase + wc * 64 + p * 16 + cl;
            const int bb = px >> 16, pin = px & 65535;
            const size_t base = ((size_t)bb * out_c + (oc - oc_off)) * HWPIX + pin;
            #pragma unroll
            for (int r = 0; r < 4; ++r) {
                float v = acc[o][p][r];
                if (HAS_BIAS) v += bias[oc + r];
                if (OUT_BF16) ((u16*)outv)[base + (size_t)r * HWPIX] = f2bf(v);
                else          ((float*)outv)[base + (size_t)r * HWPIX] = v;
            }
        }
    }
}

// ---------------------------------------------------------------------------
__device__ __forceinline__ void unp8(uint4 u, float* f) {
    f[0] = bf2f((u16)(u.x & 0xffff)); f[1] = bf2f((u16)(u.x >> 16));
    f[2] = bf2f((u16)(u.y & 0xffff)); f[3] = bf2f((u16)(u.y >> 16));
    f[4] = bf2f((u16)(u.z & 0xffff)); f[5] = bf2f((u16)(u.z >> 16));
    f[6] = bf2f((u16)(u.w & 0xffff)); f[7] = bf2f((u16)(u.w >> 16));
}

// One wave per (window, head); lane = query token.
__global__ __launch_bounds__(64)
void attn_win(const u16* __restrict__ qkvh,
              const float* __restrict__ rpb,
              float* __restrict__ outb, int i1_off)
{
    __shared__ float kls[64][16];
    __shared__ float vls[64][16];
    const int bid = blockIdx.x;               // 16384 blocks
    const int head = bid & 15;
    const int m = bid >> 4;                   // 0..1023
    const int b = m >> 9, i1l = (m >> 5) & 15, i3 = m & 31;
    const int t = threadIdx.x;
    const int i2 = t >> 3, i4 = t & 7;
    const size_t toff = (size_t)b * 25165824 + (size_t)i1l * 1572864 +
                        (size_t)i2 * 196608 + (size_t)i3 * 6144 + (size_t)i4 * 768 +
                        (size_t)head * 16;
    const uint4* qp = (const uint4*)(qkvh + toff);
    const uint4 q0 = qp[0],  q1 = qp[1];
    const uint4 k0 = qp[32], k1 = qp[33];
    const uint4 v0 = qp[64], v1 = qp[65];
    float qf[16], tmp[16];
    unp8(q0, qf); unp8(q1, qf + 8);
    unp8(k0, tmp); unp8(k1, tmp + 8);
    #pragma unroll
    for (int d = 0; d < 16; ++d) kls[t][d] = tmp[d];
    unp8(v0, tmp); unp8(v1, tmp + 8);
    #pragma unroll
    for (int d = 0; d < 16; ++d) vls[t][d] = tmp[d];
    __syncthreads();

    const int qi = t >> 3, qj = t & 7;
    float s[64];
    float mx = -1e30f;
    #pragma unroll
    for (int kt = 0; kt < 64; ++kt) {
        const float4 a  = *(const float4*)&kls[kt][0];
        const float4 b4 = *(const float4*)&kls[kt][4];
        const float4 c4 = *(const float4*)&kls[kt][8];
        const float4 d4 = *(const float4*)&kls[kt][12];
        float dot = qf[0]*a.x  + qf[1]*a.y  + qf[2]*a.z  + qf[3]*a.w
                  + qf[4]*b4.x + qf[5]*b4.y + qf[6]*b4.z + qf[7]*b4.w
                  + qf[8]*c4.x + qf[9]*c4.y + qf[10]*c4.z + qf[11]*c4.w
                  + qf[12]*d4.x+ qf[13]*d4.y+ qf[14]*d4.z+ qf[15]*d4.w;
        const int ki = kt >> 3, kj = kt & 7;
        const float val = dot * 0.25f + rpb[((qi - ki + 7) * 15 + (qj - kj + 7)) * 16 + head];
        s[kt] = val;
        mx = fmaxf(mx, val);
    }
    float l = 0.f;
    #pragma unroll
    for (int kt = 0; kt < 64; ++kt) { float e = __expf(s[kt] - mx); s[kt] = e; l += e; }
    const float inv = 1.f / l;
    float o[16];
    #pragma unroll
    for (int d = 0; d < 16; ++d) o[d] = 0.f;
    #pragma unroll
    for (int kt = 0; kt < 64; ++kt) {
        const float w = s[kt];
        const float4 a  = *(const float4*)&vls[kt][0];
        const float4 b4 = *(const float4*)&vls[kt][4];
        const float4 c4 = *(const float4*)&vls[kt][8];
        const float4 d4 = *(const float4*)&vls[kt][12];
        o[0] += w*a.x;  o[1] += w*a.y;  o[2]  += w*a.z;  o[3]  += w*a.w;
        o[4] += w*b4.x; o[5] += w*b4.y; o[6]  += w*b4.z; o[7]  += w*b4.w;
        o[8] += w*c4.x; o[9] += w*c4.y; o[10] += w*c4.z; o[11] += w*c4.w;
        o[12]+= w*d4.x; o[13]+= w*d4.y; o[14] += w*d4.z; o[15] += w*d4.w;
    }
    const int n = b * 1024 + (i1l + i1_off) * 32 + i3;
    float* op = outb + ((size_t)(n * 16 + head) << 10) + t * 16;
    #pragma unroll
    for (int d = 0; d < 16; ++d) op[d] = o[d] * inv;
}

// ---------------------------------------------------------------------------
// pool_add2: outsum = 0.125*(V8+H8)(attn_ext) + local, one 32x64 tile/block.
// Sa stride 73 (73 mod 32 = 9), Sv stride 65 — all phases <=2 words/bank.
__global__ __launch_bounds__(256)
void pool_add2(const float* __restrict__ attn,   // f32 [512][65536] (d_out scratch)
               const u16* __restrict__ local,    // bf16 [512][65536]
               u16* __restrict__ outsum)         // bf16 [512][65536]
{
    __shared__ float Sa[39][73];   // attn_ext rows TH-3..TH+35, cols TW-3..TW+67
    __shared__ float Sv[32][65];   // vertical 8-sums at output coords

    const int bid   = blockIdx.x;
    const int plane = bid >> 5;
    const int tile  = bid & 31;
    const int TH    = (tile >> 2) * 32;
    const int TW    = (tile & 3) * 64;
    const int tid   = threadIdx.x;
    const float* A  = attn + (size_t)plane * HWPIX;

    // load attn_ext 39x71 (ext: 256 -> 254, outside -> 0)
    for (int idx = tid; idx < 39 * 71; idx += 256) {
        const int i = idx / 71, j = idx - i * 71;
        const int gh = TH + i - 3, gw = TW + j - 3;
        const int eh = (gh == 256) ? 254 : gh;
        const int ew = (gw == 256) ? 254 : gw;
        float v = 0.f;
        if ((unsigned)eh < 256u && (unsigned)ew < 256u) v = A[eh * 256 + ew];
        Sa[i][j] = v;
    }
    __syncthreads();

    // Phase V: column-strip sliding 8-sum. thread: col c=tid&63, rows 8g..8g+7
    {
        const int c = tid & 63, g = tid >> 6;
        float s = 0.f;
        #pragma unroll
        for (int t = 0; t < 8; ++t) s += Sa[8 * g + t][c + 3];
        #pragma unroll
        for (int q = 0; q < 8; ++q) {
            Sv[8 * g + q][c] = s;
            if (q < 7) s += Sa[8 * g + q + 8][c + 3] - Sa[8 * g + q][c + 3];
        }
    }
    __syncthreads();

    // Phase H: row-strip sliding 8-sum + combine. thread: row r=tid>>3, cols 8cb..8cb+7
    {
        const int r = tid >> 3, cb = tid & 7;
        float h = 0.f;
        #pragma unroll
        for (int t = 0; t < 8; ++t) h += Sa[r + 3][8 * cb + t];
        const uint4 lv = *(const uint4*)(local + (size_t)plane * HWPIX +
                                         (TH + r) * 256 + TW + 8 * cb);
        float lf[8];
        unp8(lv, lf);
        u16 res[8];
        #pragma unroll
        for (int q = 0; q < 8; ++q) {
            const int ox = 8 * cb + q;
            res[q] = f2bf(0.125f * (Sv[r][ox] + h) + lf[q]);
            if (q < 7) h += Sa[r + 3][ox + 8] - Sa[r + 3][ox];
        }
        uint4 pk;
        pk.x = (unsigned)res[0] | ((unsigned)res[1] << 16);
        pk.y = (unsigned)res[2] | ((unsigned)res[3] << 16);
        pk.z = (unsigned)res[4] | ((unsigned)res[5] << 16);
        pk.w = (unsigned)res[6] | ((unsigned)res[7] << 16);
        *(uint4*)(outsum + (size_t)plane * HWPIX + (TH + r) * 256 + TW + 8 * cb) = pk;
    }
}

// ---------------------------------------------------------------------------
// dwconv3: reflect(0,1)+zero-pad(3) + depthwise 8x8, register-blocked 2x4
// outputs/thread via ds_read_b128 (stride 76: uniform 8 words/bank).
__global__ __launch_bounds__(256)
void dwconv3(const u16* __restrict__ outsum, const float* __restrict__ wdw,
             u16* __restrict__ dwo)
{
    __shared__ __align__(16) float Sp[39][76];
    __shared__ float wk[64];

    const int bid   = blockIdx.x;
    const int plane = bid >> 5;
    const int c     = plane & 255;
    const int tile  = bid & 31;
    const int TH    = (tile >> 2) * 32;
    const int TW    = (tile & 3) * 64;
    const int tid   = threadIdx.x;
    const u16* A    = outsum + (size_t)plane * HWPIX;

    if (tid < 64) wk[tid] = wdw[c * 64 + tid];

    for (int idx = tid; idx < 39 * 71; idx += 256) {
        const int i = idx / 71, j = idx - i * 71;
        const int gh = TH + i - 3, gw = TW + j - 3;
        const int eh = (gh == 256) ? 254 : gh;
        const int ew = (gw == 256) ? 254 : gw;
        float v = 0.f;
        if ((unsigned)eh < 256u && (unsigned)ew < 256u) v = bf2f(A[eh * 256 + ew]);
        Sp[i][j] = v;
    }
    __syncthreads();

    float wreg[64];
    #pragma unroll
    for (int i = 0; i < 64; ++i) wreg[i] = wk[i];

    const int rb = tid >> 4;               // 16 row-blocks of 2
    const int cb = tid & 15;               // 16 col-blocks of 4
    const int oy2 = rb * 2, ox4 = cb * 4;
    float acc[2][4];
    #pragma unroll
    for (int q = 0; q < 2; ++q)
        #pragma unroll
        for (int j = 0; j < 4; ++j) acc[q][j] = 0.f;

    #pragma unroll
    for (int r = 0; r < 9; ++r) {
        const float4 ra  = *(const float4*)&Sp[oy2 + r][ox4];
        const float4 rb4 = *(const float4*)&Sp[oy2 + r][ox4 + 4];
        const float4 rc  = *(const float4*)&Sp[oy2 + r][ox4 + 8];
        const float row[12] = {ra.x, ra.y, ra.z, ra.w, rb4.x, rb4.y, rb4.z, rb4.w,
                               rc.x, rc.y, rc.z, rc.w};
        #pragma unroll
        for (int q = 0; q < 2; ++q) {
            const int kh = r - q;
            if (kh >= 0 && kh < 8) {
                #pragma unroll
                for (int kw = 0; kw < 8; ++kw) {
                    const float w = wreg[kh * 8 + kw];
                    #pragma unroll
                    for (int j = 0; j < 4; ++j)
                        acc[q][j] += w * row[j + kw];
                }
            }
        }
    }
    u16* O = dwo + (size_t)plane * HWPIX;
    #pragma unroll
    for (int q = 0; q < 2; ++q) {
        ushort4 pk;
        pk.x = f2bf(acc[q][0]); pk.y = f2bf(acc[q][1]);
        pk.z = f2bf(acc[q][2]); pk.w = f2bf(acc[q][3]);
        *(ushort4*)&O[(TH + oy2 + q) * 256 + TW + ox4] = pk;
    }
}

// ---------------------------------------------------------------------------
extern "C" void kernel_launch(void* const* d_in, const int* in_sizes, int n_in,
                              void* d_out, int out_size, void* d_ws, size_t ws_size,
                              hipStream_t stream)
{
    const float* x     = (const float*)d_in[0];
    const float* w_qkv = (const float*)d_in[1];
    const float* w_l1  = (const float*)d_in[2];
    const float* bn1g  = (const float*)d_in[3];
    const float* bn1b  = (const float*)d_in[4];
    const float* w_l2  = (const float*)d_in[5];
    const float* bn2g  = (const float*)d_in[6];
    const float* bn2b  = (const float*)d_in[7];
    const float* w_dw  = (const float*)d_in[8];
    const float* bn3g  = (const float*)d_in[9];
    const float* bn3b  = (const float*)d_in[10];
    const float* w_pw  = (const float*)d_in[11];
    const float* rpb   = (const float*)d_in[12];
    float* out = (float*)d_out;
    char* ws = (char*)d_ws;

    if (ws_size < (size_t)236587520) return;

    // region A [0, 64MiB): x_t, later dwt
    u16* x_t = (u16*)(ws + 0);
    u16* dwt = (u16*)(ws + 0);
    // region B [64MiB, 160MiB): qkv half; first 64MiB reused as outsum after attn
    u16* qkvh   = (u16*)(ws + 67108864);
    u16* outsum = (u16*)(ws + 67108864);
    // region C [160MiB, 224MiB): local bf16, later dw_nchw bf16
    u16* localb  = (u16*)(ws + 167772160);
    u16* dw_nchw = (u16*)(ws + 167772160);
    // weights
    u16*   wl      = (u16*)(ws + 234881024);
    u16*   wq      = (u16*)(ws + 236060672);
    u16*   wpw     = (u16*)(ws + 236453888);
    float* bias_l  = (float*)(ws + 236584960);
    float* bias_pw = (float*)(ws + 236585984);
    u16*   zeros   = (u16*)(ws + 236587008);
    float* attnf = out;                        // d_out as f32 attn scratch

    prep_weights<<<1024, 256, 0, stream>>>(w_qkv, w_l1, bn1g, bn1b, w_l2, bn2g, bn2b,
                                           w_pw, bn3g, bn3b, wl, wq, wpw, bias_l, bias_pw, zeros);
    to_chlast<float><<<NPIX / 64, 256, 0, stream>>>(x, x_t);
    gemm_conv<9, true, true><<<dim3(NPIX / 128, 2), 256, 0, stream>>>(
        x_t, wl, bias_l, localb, zeros, 0, 256);
    gemm_conv<1, true, false><<<dim3(NPIX / 128, 3), 256, 0, stream>>>(
        x_t, wq, nullptr, qkvh, zeros, 0, 384);
    attn_win<<<16384, 64, 0, stream>>>(qkvh, rpb, attnf, 0);
    gemm_conv<1, true, false><<<dim3(NPIX / 128, 3), 256, 0, stream>>>(
        x_t, wq, nullptr, qkvh, zeros, 384, 384);
    attn_win<<<16384, 64, 0, stream>>>(qkvh, rpb, attnf, 16);
    // pools + local add -> bf16 outsum (overwrites first 64MiB of qkv region)
    pool_add2<<<16384, 256, 0, stream>>>(attnf, localb, outsum);
    // depthwise 8x8 -> bf16 NCHW (overwrites local region)
    dwconv3<<<16384, 256, 0, stream>>>(outsum, w_dw, dw_nchw);
    to_chlast<u16><<<NPIX / 64, 256, 0, stream>>>(dw_nchw, dwt);
    gemm_conv<1, false, true><<<dim3(NPIX / 128, 2), 256, 0, stream>>>(
        dwt, wpw, bias_pw, out, zeros, 0, 256);
}

// Round 5
// 811.660 us; speedup vs baseline: 1.2400x; 1.0368x over previous
//
#include <hip/hip_runtime.h>
#include <hip/hip_bf16.h>

// GlobalLocalAttention on MI355X — 8-phase 256² GEMM for conv3x3 + pointwise.
// Regions: A=[0,64MiB) x_t -> dwt ; B=[64,160MiB) qkvh -> outsum(bf16, first 64MiB) ;
//          C=[160,224MiB) local(bf16) -> dw_nchw(bf16) ; W=weights (~1.7MB).
// d_out doubles as the f32 attention-output scratch (final GEMM rewrites it).

typedef __bf16 bf16x8 __attribute__((ext_vector_type(8)));
typedef float  f32x4  __attribute__((ext_vector_type(4)));
typedef unsigned short u16;

#define HWPIX 65536
#define NPIX  131072

__device__ __forceinline__ u16 f2bf(float f) {
    union { float f; unsigned u; } v; v.f = f;
    return (u16)((v.u + 0x7fffu + ((v.u >> 16) & 1u)) >> 16);
}
__device__ __forceinline__ float bf2f(u16 h) {
    union { unsigned u; float f; } v; v.u = ((unsigned)h) << 16;
    return v.f;
}

#define GLDS16(gp, lp) __builtin_amdgcn_global_load_lds( \
    (__attribute__((address_space(1))) void*)(gp), \
    (__attribute__((address_space(3))) void*)(lp), 16, 0, 0)

template <int V> struct IC { static constexpr int value = V; };

// ---------------------------------------------------------------------------
__global__ void prep_weights(const float* __restrict__ w_qkv,
                             const float* __restrict__ w_l1,
                             const float* __restrict__ bn1g, const float* __restrict__ bn1b,
                             const float* __restrict__ w_l2,
                             const float* __restrict__ bn2g, const float* __restrict__ bn2b,
                             const float* __restrict__ w_pw,
                             const float* __restrict__ bn3g, const float* __restrict__ bn3b,
                             u16* __restrict__ wl, u16* __restrict__ wq, u16* __restrict__ wpw,
                             float* __restrict__ bias_l, float* __restrict__ bias_pw,
                             u16* __restrict__ zeros)
{
    const int tid = threadIdx.x;
    if (blockIdx.x >= 256) {
        int row = blockIdx.x - 256;              // 0..767
        wq[row * 256 + tid] = f2bf(w_qkv[row * 256 + tid]);
        return;
    }
    const int oc = blockIdx.x, ic = tid;
    const float rs = rsqrtf(1.f + 1e-5f);
    const float s1 = bn1g[oc] * rs;
    const float s2 = bn2g[oc] * rs;
    const float w2v = w_l2[oc * 256 + ic] * s2;
    #pragma unroll
    for (int tap = 0; tap < 9; ++tap) {
        float v = s1 * w_l1[(oc * 256 + ic) * 9 + tap];
        if (tap == 4) v += w2v;
        wl[oc * 2304 + tap * 256 + ic] = f2bf(v);
    }
    const float s3 = bn3g[ic] * rs;
    const float wp = w_pw[oc * 256 + ic];
    wpw[oc * 256 + ic] = f2bf(wp * s3);

    __shared__ float red[256];
    red[ic] = wp * bn3b[ic];
    __syncthreads();
    for (int s = 128; s > 0; s >>= 1) {
        if (ic < s) red[ic] += red[ic + s];
        __syncthreads();
    }
    if (ic == 0) {
        bias_pw[oc] = red[0];
        bias_l[oc]  = bn1b[oc] + bn2b[oc];
    }
    if (blockIdx.x == 0) zeros[tid] = 0;
}

// ---------------------------------------------------------------------------
template <typename TIN>
__device__ __forceinline__ float ldval(const TIN* p);
template <> __device__ __forceinline__ float ldval<float>(const float* p) { return *p; }
template <> __device__ __forceinline__ float ldval<u16>(const u16* p)     { return bf2f(*p); }

template <typename TIN>
__global__ __launch_bounds__(256)
void to_chlast(const TIN* __restrict__ in, u16* __restrict__ out)
{
    __shared__ float L[32][65];
    const int tid = threadIdx.x;
    const int p0 = blockIdx.x * 64;
    const int b = p0 >> 16, pin = p0 & 65535;
    const TIN* src = in + (size_t)b * 256 * HWPIX + pin;
    for (int cb = 0; cb < 256; cb += 32) {
        #pragma unroll
        for (int e = 0; e < 8; ++e) {
            int idx = e * 256 + tid;
            int row = idx >> 6, px = idx & 63;
            L[row][px] = ldval(src + (size_t)(cb + row) * HWPIX + px);
        }
        __syncthreads();
        const int px = tid >> 2, cq = tid & 3;
        u16 t[8];
        #pragma unroll
        for (int e = 0; e < 8; ++e) t[e] = f2bf(L[cq * 8 + e][px]);
        uint4 v;
        v.x = (unsigned)t[0] | ((unsigned)t[1] << 16);
        v.y = (unsigned)t[2] | ((unsigned)t[3] << 16);
        v.z = (unsigned)t[4] | ((unsigned)t[5] << 16);
        v.w = (unsigned)t[6] | ((unsigned)t[7] << 16);
        *(uint4*)(out + (size_t)(p0 + px) * 256 + cb + cq * 8) = v;
        __syncthreads();
    }
}

// ---------------------------------------------------------------------------
// 8-phase 256x256 implicit-GEMM conv (1x1 or 3x3). BK=64, 8 waves, 128KB LDS,
// XOR-swizzled LDS (phys chunk = c ^ (row&7), pre-swizzled GLDS source),
// counted vmcnt(4) once per K-tile, setprio around MFMA, raw s_barrier.
// A = weights [256oc][NTAPS*256], B = x channels-last [px][256].
template <int NTAPS, bool OUT_BF16>
__global__ __launch_bounds__(512, 2)
void conv8(const u16* __restrict__ X, const u16* __restrict__ Wm,
           const float* __restrict__ bias, void* __restrict__ outv,
           const u16* __restrict__ zeros)
{
    constexpr int NT = NTAPS * 4;        // K-tiles of 64
    constexpr int KTOT = NTAPS * 256;
    __shared__ __align__(16) u16 SA[2][256 * 64];
    __shared__ __align__(16) u16 SB[2][256 * 64];

    const int tid  = threadIdx.x;
    const int wv   = tid >> 6, lane = tid & 63;
    const int wr   = wv >> 2, wc = wv & 3;       // 2M x 4N wave grid
    const int lr   = lane & 15, lh = lane >> 4;
    const int pbase = blockIdx.x * 256;          // 256 px = one image row

    f32x4 acc[2][2][4][2];
    #pragma unroll
    for (int a = 0; a < 2; ++a)
        #pragma unroll
        for (int b = 0; b < 2; ++b)
            #pragma unroll
            for (int m = 0; m < 4; ++m)
                #pragma unroll
                for (int n = 0; n < 2; ++n)
                    acc[a][b][m][n] = (f32x4){0.f, 0.f, 0.f, 0.f};

    // stage one half-tile (128 rows x 64k): 2 GLDS per wave, linear LDS dest,
    // inverse-swizzled global source chunk csrc = (lane&7) ^ (lane>>3).
    auto stageA = [&](u16* dstbuf, int j, int h) {
        const int tap = j >> 2, kc = j & 3;
        #pragma unroll
        for (int c = 0; c < 2; ++c) {
            const int rowbase = h * 128 + wv * 16 + c * 8;
            const int row = rowbase + (lane >> 3);
            const int csrc = (lane & 7) ^ (lane >> 3);
            GLDS16(Wm + (size_t)row * KTOT + tap * 256 + kc * 64 + csrc * 8,
                   dstbuf + rowbase * 64);
        }
    };
    auto stageB = [&](u16* dstbuf, int j, int h) {
        const int tap = j >> 2, kc = j & 3;
        int dy = 0, dx = 0;
        if (NTAPS == 9) { dy = tap / 3 - 1; dx = tap % 3 - 1; }
        const int h0 = (pbase & 65535) >> 8;
        const bool hok = (NTAPS == 1) || ((unsigned)(h0 + dy) < 256u);
        #pragma unroll
        for (int c = 0; c < 2; ++c) {
            const int rowbase = h * 128 + wv * 16 + c * 8;
            const int r = rowbase + (lane >> 3);       // w coordinate
            const int csrc = (lane & 7) ^ (lane >> 3);
            const int wp = r + dx;
            const u16* src = (hok && (unsigned)wp < 256u)
                ? X + (size_t)(pbase + dy * 256 + dx + r) * 256 + kc * 64 + csrc * 8
                : zeros + (lane & 7) * 16;
            GLDS16(src, dstbuf + rowbase * 64);
        }
    };

    // prologue: tile0 fully + Ah0[1], Bh1[1] (the "previous ph3" issues)
    stageA(SA[0], 0, 0); stageA(SA[0], 0, 1);
    stageB(SB[0], 0, 0); stageB(SB[0], 0, 1);
    if (NT > 1) { stageA(SA[1], 1, 0); stageB(SB[1], 1, 1); }
    asm volatile("s_waitcnt vmcnt(4)" ::: "memory");
    __builtin_amdgcn_s_barrier();

    // one phase = one block quadrant (MH,NH) over full K=64
    auto phase = [&](auto MHc, auto NHc, auto stage, int waitmode,
                     const u16* Ab, const u16* Bb) {
        constexpr int MH = decltype(MHc)::value;
        constexpr int NH = decltype(NHc)::value;
        bf16x8 af[4][2], bfv[2][2];
        #pragma unroll
        for (int m = 0; m < 4; ++m)
            #pragma unroll
            for (int kk = 0; kk < 2; ++kk) {
                const int row = MH * 128 + wr * 64 + m * 16 + lr;
                const int phys = (kk * 4 + lh) ^ (lr & 7);
                af[m][kk] = *(const bf16x8*)&Ab[row * 64 + phys * 8];
            }
        #pragma unroll
        for (int n = 0; n < 2; ++n)
            #pragma unroll
            for (int kk = 0; kk < 2; ++kk) {
                const int row = NH * 128 + wc * 32 + n * 16 + lr;
                const int phys = (kk * 4 + lh) ^ (lr & 7);
                bfv[n][kk] = *(const bf16x8*)&Bb[row * 64 + phys * 8];
            }
        stage();
        __builtin_amdgcn_s_barrier();
        if (waitmode == 0)      asm volatile("s_waitcnt lgkmcnt(0)" ::: "memory");
        else if (waitmode == 1) asm volatile("s_waitcnt vmcnt(4) lgkmcnt(0)" ::: "memory");
        else                    asm volatile("s_waitcnt vmcnt(0) lgkmcnt(0)" ::: "memory");
        __builtin_amdgcn_s_setprio(1);
        #pragma unroll
        for (int m = 0; m < 4; ++m)
            #pragma unroll
            for (int n = 0; n < 2; ++n) {
                acc[MH][NH][m][n] = __builtin_amdgcn_mfma_f32_16x16x32_bf16(
                    af[m][0], bfv[n][0], acc[MH][NH][m][n], 0, 0, 0);
                acc[MH][NH][m][n] = __builtin_amdgcn_mfma_f32_16x16x32_bf16(
                    af[m][1], bfv[n][1], acc[MH][NH][m][n], 0, 0, 0);
            }
        __builtin_amdgcn_s_setprio(0);
        __builtin_amdgcn_s_barrier();
    };

    for (int t = 0; t < NT; ++t) {
        const u16* Ab = SA[t & 1];
        const u16* Bb = SB[t & 1];
        u16* SAn = SA[(t + 1) & 1]; u16* SBn = SB[(t + 1) & 1];
        u16* SAc = SA[t & 1];       u16* SBc = SB[t & 1];
        const bool g1 = (t + 1 < NT), g2 = (t + 2 < NT);
        // ph0: Q(0,0) reads Ah0,Bh0; stage Ah1[t+1] (other buffer, readers done)
        phase(IC<0>{}, IC<0>{}, [&] { if (g1) stageA(SAn, t + 1, 1); }, 0, Ab, Bb);
        // ph1: Q(1,1) reads Ah1,Bh1; stage Bh0[t+1]
        phase(IC<1>{}, IC<1>{}, [&] { if (g1) stageB(SBn, t + 1, 0); }, 0, Ab, Bb);
        // ph2: Q(0,1) reads Ah0,Bh1 (their last readers)
        phase(IC<0>{}, IC<1>{}, [&] {}, 0, Ab, Bb);
        // ph3: Q(1,0) reads Ah1,Bh0; stage Ah0/Bh1[t+2] into current buffer
        //      (their last reader was ph2); vmcnt(4) leaves only these in flight
        phase(IC<1>{}, IC<0>{}, [&] { if (g2) { stageA(SAc, t + 2, 0);
                                                stageB(SBc, t + 2, 1); } },
              g2 ? 1 : 2, Ab, Bb);
    }

    // epilogue: D row=oc=(lane>>4)*4+r, col=px=lane&15
    #pragma unroll
    for (int mh = 0; mh < 2; ++mh)
        #pragma unroll
        for (int m = 0; m < 4; ++m) {
            const int oc = mh * 128 + wr * 64 + m * 16 + lh * 4;
            #pragma unroll
            for (int nh = 0; nh < 2; ++nh)
                #pragma unroll
                for (int n = 0; n < 2; ++n) {
                    const int px = pbase + nh * 128 + wc * 32 + n * 16 + lr;
                    const int bb = px >> 16, pin = px & 65535;
                    #pragma unroll
                    for (int r = 0; r < 4; ++r) {
                        float v = acc[mh][nh][m][n][r] + bias[oc + r];
                        const size_t idx = ((size_t)(bb * 256 + oc + r)) * HWPIX + pin;
                        if (OUT_BF16) ((u16*)outv)[idx] = f2bf(v);
                        else          ((float*)outv)[idx] = v;
                    }
                }
        }
}

// ---------------------------------------------------------------------------
// m97-structure GEMM kept for the qkv halves (M=384, not a 256 multiple).
template <int NTAPS, bool OUT_BF16, bool HAS_BIAS>
__global__ __launch_bounds__(256)
void gemm_conv(const u16* __restrict__ X,
               const u16* __restrict__ Wm,
               const float* __restrict__ bias,
               void* __restrict__ outv,
               const u16* __restrict__ zeros,
               int oc_off, int out_c)
{
    constexpr int K = NTAPS * 256;
    __shared__ __align__(16) u16 Wt[128 * 32];
    __shared__ __align__(16) u16 Xt[128 * 32];

    const int tid   = threadIdx.x;
    const int wv    = tid >> 6;
    const int lane  = tid & 63;
    const int pbase = blockIdx.x * 128;
    const int obase = blockIdx.y * 128 + oc_off;
    const int srow  = wv * 16 + (lane >> 2);
    const int sslot = lane & 3;
    const int wr = wv >> 1, wc = wv & 1;

    f32x4 acc[4][4];
    #pragma unroll
    for (int o = 0; o < 4; ++o)
        #pragma unroll
        for (int p = 0; p < 4; ++p)
            acc[o][p] = (f32x4){0.f, 0.f, 0.f, 0.f};

    for (int tap = 0; tap < NTAPS; ++tap) {
        const u16* xsrc[2];
        const u16* wsrc[2];
        #pragma unroll
        for (int i = 0; i < 2; ++i) {
            const int row = i * 64 + srow;
            const int p = pbase + row;
            const u16* sp;
            if (NTAPS == 9) {
                const int dy = tap / 3 - 1, dx = tap % 3 - 1;
                const int h = (p >> 8) & 255, w = p & 255;
                const int hh = h + dy, ww = w + dx;
                if ((unsigned)hh < 256u && (unsigned)ww < 256u)
                    sp = X + (size_t)(p + dy * 256 + dx) * 256 + sslot * 8;
                else
                    sp = zeros + sslot * 8;
            } else {
                sp = X + (size_t)p * 256 + sslot * 8;
            }
            xsrc[i] = sp;
            wsrc[i] = Wm + (size_t)(obase + row) * K + tap * 256 + sslot * 8;
        }

        for (int kc = 0; kc < 256; kc += 32) {
            GLDS16(wsrc[0] + kc, &Wt[(wv * 16) * 32]);
            GLDS16(wsrc[1] + kc, &Wt[(64 + wv * 16) * 32]);
            GLDS16(xsrc[0] + kc, &Xt[(wv * 16) * 32]);
            GLDS16(xsrc[1] + kc, &Xt[(64 + wv * 16) * 32]);
            __syncthreads();

            bf16x8 afr[4], bfr[4];
            #pragma unroll
            for (int o = 0; o < 4; ++o)
                afr[o] = *(const bf16x8*)&Wt[(wr * 64 + o * 16 + (lane & 15)) * 32 + (lane >> 4) * 8];
            #pragma unroll
            for (int p = 0; p < 4; ++p)
                bfr[p] = *(const bf16x8*)&Xt[(wc * 64 + p * 16 + (lane & 15)) * 32 + (lane >> 4) * 8];
            #pragma unroll
            for (int o = 0; o < 4; ++o)
                #pragma unroll
                for (int p = 0; p < 4; ++p)
                    acc[o][p] = __builtin_amdgcn_mfma_f32_16x16x32_bf16(afr[o], bfr[p], acc[o][p], 0, 0, 0);
            __syncthreads();
        }
    }

    const int r0 = (lane >> 4) * 4;
    const int cl = lane & 15;
    #pragma unroll
    for (int o = 0; o < 4; ++o) {
        const int oc = obase + wr * 64 + o * 16 + r0;
        #pragma unroll
        for (int p = 0; p < 4; ++p) {
            const int px = pbase + wc * 64 + p * 16 + cl;
            const int bb = px >> 16, pin = px & 65535;
            const size_t base = ((size_t)bb * out_c + (oc - oc_off)) * HWPIX + pin;
            #pragma unroll
            for (int r = 0; r < 4; ++r) {
                float v = acc[o][p][r];
                if (HAS_BIAS) v += bias[oc + r];
                if (OUT_BF16) ((u16*)outv)[base + (size_t)r * HWPIX] = f2bf(v);
                else          ((float*)outv)[base + (size_t)r * HWPIX] = v;
            }
        }
    }
}

// ---------------------------------------------------------------------------
__device__ __forceinline__ void unp8(uint4 u, float* f) {
    f[0] = bf2f((u16)(u.x & 0xffff)); f[1] = bf2f((u16)(u.x >> 16));
    f[2] = bf2f((u16)(u.y & 0xffff)); f[3] = bf2f((u16)(u.y >> 16));
    f[4] = bf2f((u16)(u.z & 0xffff)); f[5] = bf2f((u16)(u.z >> 16));
    f[6] = bf2f((u16)(u.w & 0xffff)); f[7] = bf2f((u16)(u.w >> 16));
}

// One wave per (window, head); lane = query token.
__global__ __launch_bounds__(64)
void attn_win(const u16* __restrict__ qkvh,
              const float* __restrict__ rpb,
              float* __restrict__ outb, int i1_off)
{
    __shared__ float kls[64][16];
    __shared__ float vls[64][16];
    const int bid = blockIdx.x;               // 16384 blocks
    const int head = bid & 15;
    const int m = bid >> 4;                   // 0..1023
    const int b = m >> 9, i1l = (m >> 5) & 15, i3 = m & 31;
    const int t = threadIdx.x;
    const int i2 = t >> 3, i4 = t & 7;
    const size_t toff = (size_t)b * 25165824 + (size_t)i1l * 1572864 +
                        (size_t)i2 * 196608 + (size_t)i3 * 6144 + (size_t)i4 * 768 +
                        (size_t)head * 16;
    const uint4* qp = (const uint4*)(qkvh + toff);
    const uint4 q0 = qp[0],  q1 = qp[1];
    const uint4 k0 = qp[32], k1 = qp[33];
    const uint4 v0 = qp[64], v1 = qp[65];
    float qf[16], tmp[16];
    unp8(q0, qf); unp8(q1, qf + 8);
    unp8(k0, tmp); unp8(k1, tmp + 8);
    #pragma unroll
    for (int d = 0; d < 16; ++d) kls[t][d] = tmp[d];
    unp8(v0, tmp); unp8(v1, tmp + 8);
    #pragma unroll
    for (int d = 0; d < 16; ++d) vls[t][d] = tmp[d];
    __syncthreads();

    const int qi = t >> 3, qj = t & 7;
    float s[64];
    float mx = -1e30f;
    #pragma unroll
    for (int kt = 0; kt < 64; ++kt) {
        const float4 a  = *(const float4*)&kls[kt][0];
        const float4 b4 = *(const float4*)&kls[kt][4];
        const float4 c4 = *(const float4*)&kls[kt][8];
        const float4 d4 = *(const float4*)&kls[kt][12];
        float dot = qf[0]*a.x  + qf[1]*a.y  + qf[2]*a.z  + qf[3]*a.w
                  + qf[4]*b4.x + qf[5]*b4.y + qf[6]*b4.z + qf[7]*b4.w
                  + qf[8]*c4.x + qf[9]*c4.y + qf[10]*c4.z + qf[11]*c4.w
                  + qf[12]*d4.x+ qf[13]*d4.y+ qf[14]*d4.z+ qf[15]*d4.w;
        const int ki = kt >> 3, kj = kt & 7;
        const float val = dot * 0.25f + rpb[((qi - ki + 7) * 15 + (qj - kj + 7)) * 16 + head];
        s[kt] = val;
        mx = fmaxf(mx, val);
    }
    float l = 0.f;
    #pragma unroll
    for (int kt = 0; kt < 64; ++kt) { float e = __expf(s[kt] - mx); s[kt] = e; l += e; }
    const float inv = 1.f / l;
    float o[16];
    #pragma unroll
    for (int d = 0; d < 16; ++d) o[d] = 0.f;
    #pragma unroll
    for (int kt = 0; kt < 64; ++kt) {
        const float w = s[kt];
        const float4 a  = *(const float4*)&vls[kt][0];
        const float4 b4 = *(const float4*)&vls[kt][4];
        const float4 c4 = *(const float4*)&vls[kt][8];
        const float4 d4 = *(const float4*)&vls[kt][12];
        o[0] += w*a.x;  o[1] += w*a.y;  o[2]  += w*a.z;  o[3]  += w*a.w;
        o[4] += w*b4.x; o[5] += w*b4.y; o[6]  += w*b4.z; o[7]  += w*b4.w;
        o[8] += w*c4.x; o[9] += w*c4.y; o[10] += w*c4.z; o[11] += w*c4.w;
        o[12]+= w*d4.x; o[13]+= w*d4.y; o[14] += w*d4.z; o[15] += w*d4.w;
    }
    const int n = b * 1024 + (i1l + i1_off) * 32 + i3;
    float* op = outb + ((size_t)(n * 16 + head) << 10) + t * 16;
    #pragma unroll
    for (int d = 0; d < 16; ++d) op[d] = o[d] * inv;
}

// ---------------------------------------------------------------------------
// pool_add2: outsum = 0.125*(V8+H8)(attn_ext) + local, one 32x64 tile/block.
__global__ __launch_bounds__(256)
void pool_add2(const float* __restrict__ attn,
               const u16* __restrict__ local,
               u16* __restrict__ outsum)
{
    __shared__ float Sa[39][73];
    __shared__ float Sv[32][65];

    const int bid   = blockIdx.x;
    const int plane = bid >> 5;
    const int tile  = bid & 31;
    const int TH    = (tile >> 2) * 32;
    const int TW    = (tile & 3) * 64;
    const int tid   = threadIdx.x;
    const float* A  = attn + (size_t)plane * HWPIX;

    for (int idx = tid; idx < 39 * 71; idx += 256) {
        const int i = idx / 71, j = idx - i * 71;
        const int gh = TH + i - 3, gw = TW + j - 3;
        const int eh = (gh == 256) ? 254 : gh;
        const int ew = (gw == 256) ? 254 : gw;
        float v = 0.f;
        if ((unsigned)eh < 256u && (unsigned)ew < 256u) v = A[eh * 256 + ew];
        Sa[i][j] = v;
    }
    __syncthreads();

    {
        const int c = tid & 63, g = tid >> 6;
        float s = 0.f;
        #pragma unroll
        for (int t = 0; t < 8; ++t) s += Sa[8 * g + t][c + 3];
        #pragma unroll
        for (int q = 0; q < 8; ++q) {
            Sv[8 * g + q][c] = s;
            if (q < 7) s += Sa[8 * g + q + 8][c + 3] - Sa[8 * g + q][c + 3];
        }
    }
    __syncthreads();

    {
        const int r = tid >> 3, cb = tid & 7;
        float h = 0.f;
        #pragma unroll
        for (int t = 0; t < 8; ++t) h += Sa[r + 3][8 * cb + t];
        const uint4 lv = *(const uint4*)(local + (size_t)plane * HWPIX +
                                         (TH + r) * 256 + TW + 8 * cb);
        float lf[8];
        unp8(lv, lf);
        u16 res[8];
        #pragma unroll
        for (int q = 0; q < 8; ++q) {
            const int ox = 8 * cb + q;
            res[q] = f2bf(0.125f * (Sv[r][ox] + h) + lf[q]);
            if (q < 7) h += Sa[r + 3][ox + 8] - Sa[r + 3][ox];
        }
        uint4 pk;
        pk.x = (unsigned)res[0] | ((unsigned)res[1] << 16);
        pk.y = (unsigned)res[2] | ((unsigned)res[3] << 16);
        pk.z = (unsigned)res[4] | ((unsigned)res[5] << 16);
        pk.w = (unsigned)res[6] | ((unsigned)res[7] << 16);
        *(uint4*)(outsum + (size_t)plane * HWPIX + (TH + r) * 256 + TW + 8 * cb) = pk;
    }
}

// ---------------------------------------------------------------------------
// dwconv3: reflect(0,1)+zero-pad(3) + depthwise 8x8, register-blocked 2x4.
__global__ __launch_bounds__(256)
void dwconv3(const u16* __restrict__ outsum, const float* __restrict__ wdw,
             u16* __restrict__ dwo)
{
    __shared__ __align__(16) float Sp[39][76];
    __shared__ float wk[64];

    const int bid   = blockIdx.x;
    const int plane = bid >> 5;
    const int c     = plane & 255;
    const int tile  = bid & 31;
    const int TH    = (tile >> 2) * 32;
    const int TW    = (tile & 3) * 64;
    const int tid   = threadIdx.x;
    const u16* A    = outsum + (size_t)plane * HWPIX;

    if (tid < 64) wk[tid] = wdw[c * 64 + tid];

    for (int idx = tid; idx < 39 * 71; idx += 256) {
        const int i = idx / 71, j = idx - i * 71;
        const int gh = TH + i - 3, gw = TW + j - 3;
        const int eh = (gh == 256) ? 254 : gh;
        const int ew = (gw == 256) ? 254 : gw;
        float v = 0.f;
        if ((unsigned)eh < 256u && (unsigned)ew < 256u) v = bf2f(A[eh * 256 + ew]);
        Sp[i][j] = v;
    }
    __syncthreads();

    float wreg[64];
    #pragma unroll
    for (int i = 0; i < 64; ++i) wreg[i] = wk[i];

    const int rb = tid >> 4;
    const int cb = tid & 15;
    const int oy2 = rb * 2, ox4 = cb * 4;
    float acc[2][4];
    #pragma unroll
    for (int q = 0; q < 2; ++q)
        #pragma unroll
        for (int j = 0; j < 4; ++j) acc[q][j] = 0.f;

    #pragma unroll
    for (int r = 0; r < 9; ++r) {
        const float4 ra  = *(const float4*)&Sp[oy2 + r][ox4];
        const float4 rb4 = *(const float4*)&Sp[oy2 + r][ox4 + 4];
        const float4 rc  = *(const float4*)&Sp[oy2 + r][ox4 + 8];
        const float row[12] = {ra.x, ra.y, ra.z, ra.w, rb4.x, rb4.y, rb4.z, rb4.w,
                               rc.x, rc.y, rc.z, rc.w};
        #pragma unroll
        for (int q = 0; q < 2; ++q) {
            const int kh = r - q;
            if (kh >= 0 && kh < 8) {
                #pragma unroll
                for (int kw = 0; kw < 8; ++kw) {
                    const float w = wreg[kh * 8 + kw];
                    #pragma unroll
                    for (int j = 0; j < 4; ++j)
                        acc[q][j] += w * row[j + kw];
                }
            }
        }
    }
    u16* O = dwo + (size_t)plane * HWPIX;
    #pragma unroll
    for (int q = 0; q < 2; ++q) {
        ushort4 pk;
        pk.x = f2bf(acc[q][0]); pk.y = f2bf(acc[q][1]);
        pk.z = f2bf(acc[q][2]); pk.w = f2bf(acc[q][3]);
        *(ushort4*)&O[(TH + oy2 + q) * 256 + TW + ox4] = pk;
    }
}

// ---------------------------------------------------------------------------
extern "C" void kernel_launch(void* const* d_in, const int* in_sizes, int n_in,
                              void* d_out, int out_size, void* d_ws, size_t ws_size,
                              hipStream_t stream)
{
    const float* x     = (const float*)d_in[0];
    const float* w_qkv = (const float*)d_in[1];
    const float* w_l1  = (const float*)d_in[2];
    const float* bn1g  = (const float*)d_in[3];
    const float* bn1b  = (const float*)d_in[4];
    const float* w_l2  = (const float*)d_in[5];
    const float* bn2g  = (const float*)d_in[6];
    const float* bn2b  = (const float*)d_in[7];
    const float* w_dw  = (const float*)d_in[8];
    const float* bn3g  = (const float*)d_in[9];
    const float* bn3b  = (const float*)d_in[10];
    const float* w_pw  = (const float*)d_in[11];
    const float* rpb   = (const float*)d_in[12];
    float* out = (float*)d_out;
    char* ws = (char*)d_ws;

    if (ws_size < (size_t)236587520) return;

    u16* x_t = (u16*)(ws + 0);
    u16* dwt = (u16*)(ws + 0);
    u16* qkvh   = (u16*)(ws + 67108864);
    u16* outsum = (u16*)(ws + 67108864);
    u16* localb  = (u16*)(ws + 167772160);
    u16* dw_nchw = (u16*)(ws + 167772160);
    u16*   wl      = (u16*)(ws + 234881024);
    u16*   wq      = (u16*)(ws + 236060672);
    u16*   wpw     = (u16*)(ws + 236453888);
    float* bias_l  = (float*)(ws + 236584960);
    float* bias_pw = (float*)(ws + 236585984);
    u16*   zeros   = (u16*)(ws + 236587008);
    float* attnf = out;

    prep_weights<<<1024, 256, 0, stream>>>(w_qkv, w_l1, bn1g, bn1b, w_l2, bn2g, bn2b,
                                           w_pw, bn3g, bn3b, wl, wq, wpw, bias_l, bias_pw, zeros);
    to_chlast<float><<<NPIX / 64, 256, 0, stream>>>(x, x_t);
    // conv3x3 + bias (8-phase 256² structure)
    conv8<9, true><<<NPIX / 256, 512, 0, stream>>>(x_t, wl, bias_l, localb, zeros);
    gemm_conv<1, true, false><<<dim3(NPIX / 128, 3), 256, 0, stream>>>(
        x_t, wq, nullptr, qkvh, zeros, 0, 384);
    attn_win<<<16384, 64, 0, stream>>>(qkvh, rpb, attnf, 0);
    gemm_conv<1, true, false><<<dim3(NPIX / 128, 3), 256, 0, stream>>>(
        x_t, wq, nullptr, qkvh, zeros, 384, 384);
    attn_win<<<16384, 64, 0, stream>>>(qkvh, rpb, attnf, 16);
    pool_add2<<<16384, 256, 0, stream>>>(attnf, localb, outsum);
    dwconv3<<<16384, 256, 0, stream>>>(outsum, w_dw, dw_nchw);
    to_chlast<u16><<<NPIX / 64, 256, 0, stream>>>(dw_nchw, dwt);
    // pointwise + bias (8-phase 256² structure) -> final f32 output
    conv8<1, false><<<NPIX / 256, 512, 0, stream>>>(dwt, wpw, bias_pw, out, zeros);
}